// Round 1
// 2057.798 us; speedup vs baseline: 1.5243x; 1.5243x over previous
//
#include <hip/hip_runtime.h>
#include <hip/hip_bf16.h>
#include <math.h>

typedef __hip_bfloat16 bf16;
typedef __attribute__((ext_vector_type(8))) short short8;
typedef __attribute__((ext_vector_type(4))) short short4v;
typedef __attribute__((ext_vector_type(4))) float floatx4;

#define DEV static __device__ __forceinline__

DEV float bf2f(unsigned short u) {
  union { unsigned int i; float f; } x;
  x.i = ((unsigned int)u) << 16;
  return x.f;
}
DEV unsigned short f2bf_bits(float f) {
  union { bf16 h; unsigned short u; } x;
  x.h = __float2bfloat16(f);
  return x.u;
}
DEV short8 cvt8(float4 a, float4 b) {
  short8 r;
  r[0] = (short)f2bf_bits(a.x); r[1] = (short)f2bf_bits(a.y);
  r[2] = (short)f2bf_bits(a.z); r[3] = (short)f2bf_bits(a.w);
  r[4] = (short)f2bf_bits(b.x); r[5] = (short)f2bf_bits(b.y);
  r[6] = (short)f2bf_bits(b.z); r[7] = (short)f2bf_bits(b.w);
  return r;
}

// async global->LDS, 16B per lane. LDS dest must be wave-uniform base + lane*16,
// which our staging layout satisfies (byte = 16*tid + 4096*t).
DEV void gload_lds16(const unsigned short* g, unsigned short* l) {
  __builtin_amdgcn_global_load_lds((const __attribute__((address_space(1))) void*)g,
                                   (__attribute__((address_space(3))) void*)l,
                                   16, 0, 0);
}

// window-gather (chunk-local): window-row -> source row (fuses roll(-4,-4)+partition)
DEV int gather_win_row(int wr) {
  int bw = wr >> 6, n = wr & 63;
  int bt = bw >> 2, w2 = bw & 3;
  int wi = w2 >> 1, wj = w2 & 1;
  int r = n >> 3, c = n & 7;
  int sr = (wi * 8 + r + 4) & 15;
  int sc = (wj * 8 + c + 4) & 15;
  return bt * 256 + sr * 16 + sc;
}

enum { BIAS_SIMPLE = 0, BIAS_QKV = 1 };
enum { ACT_NONE = 0, ACT_GELU = 1 };

// f32 -> bf16 bulk convert, 8 elems/thread. n must be a multiple of 2048 (it is).
__global__ __launch_bounds__(256) void cvt_bf16(const float* __restrict__ in,
                                                bf16* __restrict__ out, int n) {
  int i = (blockIdx.x * 256 + threadIdx.x) * 8;
  if (i >= n) return;
  float4 a = *reinterpret_cast<const float4*>(in + i);
  float4 b = *reinterpret_cast<const float4*>(in + i + 4);
  *reinterpret_cast<short8*>((unsigned short*)out + i) = cvt8(a, b);
}

// C[M,N] = act(A[M,K] @ B[N,K]^T + bias). A,B bf16 (pre-converted), bias f32,
// C bf16, fp32 accum via MFMA. BM=BN=128, BK=64, 256 threads = 4 waves (2x2).
// m97 structure: global_load_lds dwordx4 staging, 2-barrier K-loop.
template <int GATHER, int BIASMODE, int ACT>
__global__ __launch_bounds__(256, 2) void gemm_bt(
    const unsigned short* __restrict__ A, const unsigned short* __restrict__ B,
    const float* __restrict__ bias0, const float* __restrict__ bias1,
    bf16* __restrict__ C, int M, int N, int K)
{
  __shared__ __align__(16) unsigned short As[128 * 64];
  __shared__ __align__(16) unsigned short Bs[128 * 64];
  const int tid = threadIdx.x;
  const int lane = tid & 63;
  const int wave = tid >> 6;
  const int waveM = wave >> 1, waveN = wave & 1;
  const int tileM = blockIdx.x * 128, tileN = blockIdx.y * 128;

  const int row0 = tid >> 3;          // 0..31
  const int kOff = (tid & 7) * 8;     // bf16 elem offset within row (16B steps)

  const unsigned short* ag[4];
  const unsigned short* bg[4];
  unsigned short* al[4];
  unsigned short* bl[4];
#pragma unroll
  for (int t = 0; t < 4; ++t) {
    int gr = tileM + row0 + 32 * t;
    int sr = GATHER ? gather_win_row(gr) : gr;
    ag[t] = A + (size_t)sr * (size_t)K + (size_t)kOff;
    bg[t] = B + (size_t)(tileN + row0 + 32 * t) * (size_t)K + (size_t)kOff;
    al[t] = &As[(row0 + 32 * t) * 64 + kOff];
    bl[t] = &Bs[(row0 + 32 * t) * 64 + kOff];
  }

  floatx4 acc[4][4];
#pragma unroll
  for (int i = 0; i < 4; ++i)
#pragma unroll
    for (int j = 0; j < 4; ++j) acc[i][j] = (floatx4){0.f, 0.f, 0.f, 0.f};

  for (int k0 = 0; k0 < K; k0 += 64) {
#pragma unroll
    for (int t = 0; t < 4; ++t) {
      gload_lds16(ag[t] + k0, al[t]);
      gload_lds16(bg[t] + k0, bl[t]);
    }
    __syncthreads();   // drains vmcnt -> LDS tile ready
#pragma unroll
    for (int ks = 0; ks < 2; ++ks) {
      const int kk = ks * 32 + (lane >> 4) * 8;
      short8 af[4], bfv[4];
#pragma unroll
      for (int i = 0; i < 4; ++i)
        af[i] = *reinterpret_cast<const short8*>(
            &As[(waveM * 64 + i * 16 + (lane & 15)) * 64 + kk]);
#pragma unroll
      for (int j = 0; j < 4; ++j)
        bfv[j] = *reinterpret_cast<const short8*>(
            &Bs[(waveN * 64 + j * 16 + (lane & 15)) * 64 + kk]);
#pragma unroll
      for (int i = 0; i < 4; ++i)
#pragma unroll
        for (int j = 0; j < 4; ++j)
          acc[i][j] = __builtin_amdgcn_mfma_f32_16x16x32_bf16(af[i], bfv[j], acc[i][j], 0, 0, 0);
    }
    __syncthreads();
  }

  // epilogue: C/D layout row=(lane>>4)*4+reg, col=lane&15  [m89-verified]
#pragma unroll
  for (int j = 0; j < 4; ++j) {
    const int col = tileN + waveN * 64 + j * 16 + (lane & 15);
    float bv;
    if (BIASMODE == BIAS_QKV) {
      if (col < 1024) bv = bias0[col];
      else if (col < 2048) bv = 0.f;
      else bv = bias1[col - 2048];
    } else {
      bv = bias0[col];
    }
#pragma unroll
    for (int i = 0; i < 4; ++i) {
      const int rbase = tileM + waveM * 64 + i * 16 + ((lane >> 4) * 4);
#pragma unroll
      for (int r = 0; r < 4; ++r) {
        float v = acc[i][j][r] + bv;
        if (ACT == ACT_GELU) v = 0.5f * v * (1.f + erff(v * 0.70710678118f));
        C[(size_t)(rbase + r) * (size_t)N + col] = __float2bfloat16(v);
      }
    }
  }
}

// CPB MLP: regenerate the static log-spaced coord table and run 2->512->16 MLP.
__global__ __launch_bounds__(512) void cpb_kernel(
    const float* __restrict__ w1, const float* __restrict__ b1,
    const float* __restrict__ w2, float* __restrict__ TBL)
{
  __shared__ float hid[512];
  const int i = blockIdx.x;   // 0..224
  const int j = threadIdx.x;  // 0..511
  const float d0 = ((float)(i / 15) - 7.f) / 7.f;
  const float d1 = ((float)(i % 15) - 7.f) / 7.f;
  const float t0 = copysignf(log2f(1.f + fabsf(d0)), d0);
  const float t1 = copysignf(log2f(1.f + fabsf(d1)), d1);
  float hv = t0 * w1[j * 2] + t1 * w1[j * 2 + 1] + b1[j];
  hid[j] = fmaxf(hv, 0.f);
  __syncthreads();
  if (j < 16) {
    float s = 0.f;
    for (int jj = 0; jj < 512; ++jj) s += w2[j * 512 + jj] * hid[jj];
    TBL[i * 16 + j] = 16.f / (1.f + expf(-s));
  }
}

// attention: one wave per (window, head). cosine attn + cpb bias + shift mask + softmax + PV.
__global__ __launch_bounds__(64) void attn_kernel(
    const bf16* __restrict__ QKV, const float* __restrict__ TBL,
    const float* __restrict__ ls, bf16* __restrict__ ATT)
{
  __shared__ __align__(16) float kn[64][68];
  __shared__ __align__(16) float vvs[64][68];
  __shared__ float tb[225];
  __shared__ int ids[64];

  const int bw = blockIdx.x >> 4, h = blockIdx.x & 15;
  const int t = threadIdx.x;
  const unsigned short* qkvu = (const unsigned short*)QKV;
  const size_t rb = (size_t)(bw * 64 + t) * 3072;

  float q[64];
  float s2 = 0.f;
#pragma unroll
  for (int d0 = 0; d0 < 64; d0 += 8) {
    short8 v = *reinterpret_cast<const short8*>(&qkvu[rb + h * 64 + d0]);
#pragma unroll
    for (int j = 0; j < 8; ++j) { float f = bf2f((unsigned short)v[j]); q[d0 + j] = f; s2 += f * f; }
  }
  float inv = 1.f / fmaxf(sqrtf(s2), 1e-12f);
#pragma unroll
  for (int d = 0; d < 64; ++d) q[d] *= inv;

  s2 = 0.f;
#pragma unroll
  for (int d0 = 0; d0 < 64; d0 += 8) {
    short8 v = *reinterpret_cast<const short8*>(&qkvu[rb + 1024 + h * 64 + d0]);
#pragma unroll
    for (int j = 0; j < 8; ++j) { float f = bf2f((unsigned short)v[j]); kn[t][d0 + j] = f; s2 += f * f; }
  }
  inv = 1.f / fmaxf(sqrtf(s2), 1e-12f);
#pragma unroll
  for (int d = 0; d < 64; ++d) kn[t][d] *= inv;

#pragma unroll
  for (int d0 = 0; d0 < 64; d0 += 8) {
    short8 v = *reinterpret_cast<const short8*>(&qkvu[rb + 2048 + h * 64 + d0]);
#pragma unroll
    for (int j = 0; j < 8; ++j) vvs[t][d0 + j] = bf2f((unsigned short)v[j]);
  }

  for (int i = t; i < 225; i += 64) tb[i] = TBL[i * 16 + h];

  {
    const int w2 = bw & 3, wi = w2 >> 1, wj = w2 & 1;
    const int r = t >> 3, c = t & 7;
    const int gr = wi * 8 + r, gc = wj * 8 + c;
    const int rr = (gr < 8) ? 0 : ((gr < 12) ? 1 : 2);
    const int rc = (gc < 8) ? 0 : ((gc < 12) ? 1 : 2);
    ids[t] = rr * 3 + rc;
  }
  __syncthreads();

  const float scale = expf(fminf(ls[h], 4.60517019f));
  const int rt = t >> 3, ct = t & 7;
  const int myid = ids[t];

  float sc[64];
#pragma unroll
  for (int m = 0; m < 64; ++m) {
    const floatx4* kr = reinterpret_cast<const floatx4*>(&kn[m][0]);
    float dot = 0.f;
#pragma unroll
    for (int dq = 0; dq < 16; ++dq) {
      floatx4 kv = kr[dq];
      dot += q[4 * dq + 0] * kv[0] + q[4 * dq + 1] * kv[1] +
             q[4 * dq + 2] * kv[2] + q[4 * dq + 3] * kv[3];
    }
    const int rm = m >> 3, cm = m & 7;
    const int idx = (rt - rm + 7) * 15 + (ct - cm + 7);
    float val = dot * scale + tb[idx];
    if (ids[m] != myid) val -= 100.f;
    sc[m] = val;
  }

  float mx = -1e30f;
#pragma unroll
  for (int m = 0; m < 64; ++m) mx = fmaxf(mx, sc[m]);
  float ssum = 0.f;
#pragma unroll
  for (int m = 0; m < 64; ++m) { float e = expf(sc[m] - mx); sc[m] = e; ssum += e; }
  const float rs = 1.f / ssum;

  float out[64];
#pragma unroll
  for (int d = 0; d < 64; ++d) out[d] = 0.f;
#pragma unroll
  for (int m = 0; m < 64; ++m) {
    const float p = sc[m];
    const floatx4* vr = reinterpret_cast<const floatx4*>(&vvs[m][0]);
#pragma unroll
    for (int dq = 0; dq < 16; ++dq) {
      floatx4 vv = vr[dq];
      out[4 * dq + 0] += p * vv[0];
      out[4 * dq + 1] += p * vv[1];
      out[4 * dq + 2] += p * vv[2];
      out[4 * dq + 3] += p * vv[3];
    }
  }

  unsigned short* op = (unsigned short*)ATT + (size_t)(bw * 64 + t) * 1024 + h * 64;
#pragma unroll
  for (int d0 = 0; d0 < 64; d0 += 8) {
    union { short8 v; unsigned short u[8]; } o;
#pragma unroll
    for (int j = 0; j < 8; ++j) o.u[j] = f2bf_bits(out[d0 + j] * rs);
    *reinterpret_cast<short8*>(&op[d0]) = o.v;
  }
}

// out[tok] = base[tok] + LN(src[maprow(tok)]) ; GATHER does window-reverse + roll(+4,+4).
// src bf16; base/out are f32. WB additionally emits a bf16 copy of out (for the next GEMM's A).
template <bool GATHER, bool WB>
__global__ __launch_bounds__(256) void ln_residual(
    const bf16* __restrict__ src, const float* base,
    const float* __restrict__ gw, const float* __restrict__ gb,
    float* out, bf16* __restrict__ out_bf)
{
  const int tok = blockIdx.x;
  int srow;
  if (GATHER) {
    const int bt = tok >> 8, rem = tok & 255, i = rem >> 4, j = rem & 15;
    const int p = (i + 12) & 15, qq = (j + 12) & 15;
    srow = (bt * 4 + (p >> 3) * 2 + (qq >> 3)) * 64 + (p & 7) * 8 + (qq & 7);
  } else {
    srow = tok;
  }
  const unsigned short* sp = (const unsigned short*)src + (size_t)srow * 1024;
  const int tx = threadIdx.x;
  union { short4v v; unsigned short u[4]; } lv;
  lv.v = *reinterpret_cast<const short4v*>(&sp[tx * 4]);
  float v[4];
  float s = 0.f, sq = 0.f;
#pragma unroll
  for (int u = 0; u < 4; ++u) {
    float f = bf2f(lv.u[u]);
    v[u] = f; s += f; sq += f * f;
  }
#pragma unroll
  for (int off = 32; off > 0; off >>= 1) { s += __shfl_xor(s, off); sq += __shfl_xor(sq, off); }
  __shared__ float rs_[4], rq_[4];
  if ((tx & 63) == 0) { rs_[tx >> 6] = s; rq_[tx >> 6] = sq; }
  __syncthreads();
  s = rs_[0] + rs_[1] + rs_[2] + rs_[3];
  sq = rq_[0] + rq_[1] + rq_[2] + rq_[3];
  const float mean = s * (1.f / 1024.f);
  const float var = sq * (1.f / 1024.f) - mean * mean;
  const float rstd = rsqrtf(var + 1e-5f);

  const float* bp = base + (size_t)tok * 1024;
  float4 b4 = *reinterpret_cast<const float4*>(&bp[tx * 4]);
  float bl[4] = {b4.x, b4.y, b4.z, b4.w};
  float4 o4;
  float* ol = (float*)&o4;
#pragma unroll
  for (int u = 0; u < 4; ++u) {
    const int c = tx * 4 + u;
    ol[u] = bl[u] + (v[u] - mean) * rstd * gw[c] + gb[c];
  }
  float* op = out + (size_t)tok * 1024;
  *reinterpret_cast<float4*>(&op[tx * 4]) = o4;
  if (WB) {
    union { short4v v; unsigned short u[4]; } ob;
#pragma unroll
    for (int u = 0; u < 4; ++u) ob.u[u] = f2bf_bits(ol[u]);
    *reinterpret_cast<short4v*>((unsigned short*)out_bf + (size_t)tok * 1024 + tx * 4) = ob.v;
  }
}

extern "C" void kernel_launch(void* const* d_in, const int* in_sizes, int n_in,
                              void* d_out, int out_size, void* d_ws, size_t ws_size,
                              hipStream_t stream) {
  (void)in_sizes; (void)n_in; (void)out_size; (void)ws_size;
  const float* x      = (const float*)d_in[0];
  const float* qkv_w  = (const float*)d_in[1];
  const float* q_bias = (const float*)d_in[2];
  const float* v_bias = (const float*)d_in[3];
  const float* lscale = (const float*)d_in[4];
  const float* cpb_w1 = (const float*)d_in[5];
  const float* cpb_b1 = (const float*)d_in[6];
  const float* cpb_w2 = (const float*)d_in[7];
  const float* proj_w = (const float*)d_in[8];
  const float* proj_b = (const float*)d_in[9];
  const float* n1w    = (const float*)d_in[10];
  const float* n1b    = (const float*)d_in[11];
  const float* fc1_w  = (const float*)d_in[12];
  const float* fc1_b  = (const float*)d_in[13];
  const float* fc2_w  = (const float*)d_in[14];
  const float* fc2_b  = (const float*)d_in[15];
  const float* n2w    = (const float*)d_in[16];
  const float* n2b    = (const float*)d_in[17];
  float* out = (float*)d_out;   // reference output dtype is float32

  // Chunked over 4 groups of 8192 tokens (32 images, window-aligned).
  // Region time-sharing (peak stays at previous 100.7 MB):
  //  A [0, 67.1MB): QKV (50.3MB) -> H (67.1MB); tail [50.3,52.4MB) = proj_w bf16
  //  B [67.1, 83.9MB): qkv_w bf16 -> ATT -> XS_bf -> F2
  //  C [83.9, 100.7MB): x bf16 -> PROJ -> {fc1_w bf16, fc2_w bf16}
  //  TBL at 100.66MB
  char* ws = (char*)d_ws;
  bf16*  QKV  = (bf16*)(ws);                          // [8192,3072]
  bf16*  H    = (bf16*)(ws);                          // [8192,4096]
  bf16*  WPROJ= (bf16*)(ws + 50331648);               // [1024,1024]
  bf16*  WQKV = (bf16*)(ws + 67108864);               // [3072,1024]
  bf16*  ATT  = (bf16*)(ws + 67108864);               // [8192,1024]
  bf16*  XSB  = (bf16*)(ws + 67108864);               // [8192,1024]
  bf16*  F2   = (bf16*)(ws + 67108864);               // [8192,1024]
  bf16*  XBF  = (bf16*)(ws + 83886080);               // [8192,1024]
  bf16*  PROJ = (bf16*)(ws + 83886080);               // [8192,1024]
  bf16*  WF1  = (bf16*)(ws + 83886080);               // [4096,1024]
  bf16*  WF2  = (bf16*)(ws + 83886080 + 8388608);     // [1024,4096]
  float* TBL  = (float*)(ws + 100663296);             // [225,16] f32

  cpb_kernel<<<225, 512, 0, stream>>>(cpb_w1, cpb_b1, cpb_w2, TBL);

  for (int ch = 0; ch < 4; ++ch) {
    const size_t tokBase = (size_t)ch * 8192;
    const float* x_c = x + tokBase * 1024;
    float* out_c = out + tokBase * 1024;

    // pre-convert inputs/weights to bf16 (off the GEMM critical path)
    cvt_bf16<<<4096, 256, 0, stream>>>(x_c, XBF, 8388608);
    cvt_bf16<<<1536, 256, 0, stream>>>(qkv_w, WQKV, 3145728);
    cvt_bf16<<<512, 256, 0, stream>>>(proj_w, WPROJ, 1048576);

    // QKV with fused shift+window gather (chunk-local rows; images self-contained)
    gemm_bt<1, BIAS_QKV, ACT_NONE><<<dim3(64, 24), 256, 0, stream>>>(
        (const unsigned short*)XBF, (const unsigned short*)WQKV,
        q_bias, v_bias, QKV, 8192, 3072, 1024);
    // 128 windows x 16 heads (overwrites WQKV region with ATT - WQKV dead)
    attn_kernel<<<2048, 64, 0, stream>>>(QKV, TBL, lscale, ATT);
    gemm_bt<0, BIAS_SIMPLE, ACT_NONE><<<dim3(64, 8), 256, 0, stream>>>(
        (const unsigned short*)ATT, (const unsigned short*)WPROJ,
        proj_b, nullptr, PROJ, 8192, 1024, 1024);
    // window-reverse + roll + LN + residual; xs chunk lives in d_out (f32),
    // plus bf16 copy (XSB) for fc1's A operand
    ln_residual<true, true><<<8192, 256, 0, stream>>>(PROJ, x_c, n1w, n1b, out_c, XSB);
    // MLP weights -> bf16 (PROJ dead after ln1; reuse region C)
    cvt_bf16<<<2048, 256, 0, stream>>>(fc1_w, WF1, 4194304);
    cvt_bf16<<<2048, 256, 0, stream>>>(fc2_w, WF2, 4194304);
    gemm_bt<0, BIAS_SIMPLE, ACT_GELU><<<dim3(64, 32), 256, 0, stream>>>(
        (const unsigned short*)XSB, (const unsigned short*)WF1,
        fc1_b, nullptr, H, 8192, 4096, 1024);
    gemm_bt<0, BIAS_SIMPLE, ACT_NONE><<<dim3(64, 8), 256, 0, stream>>>(
        (const unsigned short*)H, (const unsigned short*)WF2,
        fc2_b, nullptr, F2, 8192, 1024, 4096);
    ln_residual<false, false><<<8192, 256, 0, stream>>>(F2, out_c, n2w, n2b, out_c, nullptr);
  }
}

// Round 2
// 2033.876 us; speedup vs baseline: 1.5423x; 1.0118x over previous
//
#include <hip/hip_runtime.h>
#include <hip/hip_bf16.h>
#include <math.h>

typedef __hip_bfloat16 bf16;
typedef __attribute__((ext_vector_type(8))) short short8;
typedef __attribute__((ext_vector_type(4))) short short4v;
typedef __attribute__((ext_vector_type(4))) float floatx4;

#define DEV static __device__ __forceinline__

DEV float bf2f(unsigned short u) {
  union { unsigned int i; float f; } x;
  x.i = ((unsigned int)u) << 16;
  return x.f;
}
DEV unsigned short f2bf_bits(float f) {
  union { bf16 h; unsigned short u; } x;
  x.h = __float2bfloat16(f);
  return x.u;
}
DEV short8 cvt8(float4 a, float4 b) {
  short8 r;
  r[0] = (short)f2bf_bits(a.x); r[1] = (short)f2bf_bits(a.y);
  r[2] = (short)f2bf_bits(a.z); r[3] = (short)f2bf_bits(a.w);
  r[4] = (short)f2bf_bits(b.x); r[5] = (short)f2bf_bits(b.y);
  r[6] = (short)f2bf_bits(b.z); r[7] = (short)f2bf_bits(b.w);
  return r;
}

// tanh-form GELU: v * sigmoid(1.5957691*v + 0.0713548*v^3). |err| vs exact ~1e-3.
DEV float gelu_fast(float v) {
  float y = v * (1.5957691216f + 0.0713548163f * v * v);
  return __fdividef(v, 1.f + __expf(-y));
}

// async global->LDS, 16B per lane. LDS dest must be wave-uniform base + lane*16.
DEV void gload_lds16(const unsigned short* g, unsigned short* l) {
  __builtin_amdgcn_global_load_lds((const __attribute__((address_space(1))) void*)g,
                                   (__attribute__((address_space(3))) void*)l,
                                   16, 0, 0);
}

// window-gather (chunk-local): window-row -> source row (fuses roll(-4,-4)+partition)
DEV int gather_win_row(int wr) {
  int bw = wr >> 6, n = wr & 63;
  int bt = bw >> 2, w2 = bw & 3;
  int wi = w2 >> 1, wj = w2 & 1;
  int r = n >> 3, c = n & 7;
  int sr = (wi * 8 + r + 4) & 15;
  int sc = (wj * 8 + c + 4) & 15;
  return bt * 256 + sr * 16 + sc;
}

enum { BIAS_SIMPLE = 0, BIAS_QKV = 1 };
enum { ACT_NONE = 0, ACT_GELU = 1 };

// f32 -> bf16 bulk convert, 8 elems/thread.
__global__ __launch_bounds__(256) void cvt_bf16(const float* __restrict__ in,
                                                bf16* __restrict__ out, int n) {
  int i = (blockIdx.x * 256 + threadIdx.x) * 8;
  if (i >= n) return;
  float4 a = *reinterpret_cast<const float4*>(in + i);
  float4 b = *reinterpret_cast<const float4*>(in + i + 4);
  *reinterpret_cast<short8*>((unsigned short*)out + i) = cvt8(a, b);
}

// C[M,N] = act(A[M,K] @ B[N,K]^T + bias). A,B bf16 (pre-converted), bias f32,
// C bf16, fp32 accum via MFMA. BM=BN=128, BK=64, 256 threads = 4 waves (2x2).
// m97 structure: global_load_lds dwordx4 staging, 2-barrier K-loop.
// Epilogue: LDS transpose ([128][136] bf16, 16B-aligned rows) -> dwordx4 stores.
template <int GATHER, int BIASMODE, int ACT>
__global__ __launch_bounds__(256, 2) void gemm_bt(
    const unsigned short* __restrict__ A, const unsigned short* __restrict__ B,
    const float* __restrict__ bias0, const float* __restrict__ bias1,
    bf16* __restrict__ C, int M, int N, int K)
{
  // staging (2x 8192 shorts = 32KB) and epilogue tile (128*136 shorts = 34KB) share
  __shared__ __align__(16) unsigned short sh[128 * 136];
  unsigned short* As = sh;
  unsigned short* Bs = sh + 8192;

  const int tid = threadIdx.x;
  const int lane = tid & 63;
  const int wave = tid >> 6;
  const int waveM = wave >> 1, waveN = wave & 1;
  const int tileM = blockIdx.x * 128, tileN = blockIdx.y * 128;

  const int row0 = tid >> 3;          // 0..31
  const int kOff = (tid & 7) * 8;     // bf16 elem offset within row (16B steps)

  const unsigned short* ag[4];
  const unsigned short* bg[4];
  unsigned short* al[4];
  unsigned short* bl[4];
#pragma unroll
  for (int t = 0; t < 4; ++t) {
    int gr = tileM + row0 + 32 * t;
    int sr = GATHER ? gather_win_row(gr) : gr;
    ag[t] = A + (size_t)sr * (size_t)K + (size_t)kOff;
    bg[t] = B + (size_t)(tileN + row0 + 32 * t) * (size_t)K + (size_t)kOff;
    al[t] = &As[(row0 + 32 * t) * 64 + kOff];
    bl[t] = &Bs[(row0 + 32 * t) * 64 + kOff];
  }

  floatx4 acc[4][4];
#pragma unroll
  for (int i = 0; i < 4; ++i)
#pragma unroll
    for (int j = 0; j < 4; ++j) acc[i][j] = (floatx4){0.f, 0.f, 0.f, 0.f};

  for (int k0 = 0; k0 < K; k0 += 64) {
#pragma unroll
    for (int t = 0; t < 4; ++t) {
      gload_lds16(ag[t] + k0, al[t]);
      gload_lds16(bg[t] + k0, bl[t]);
    }
    __syncthreads();   // drains vmcnt -> LDS tile ready
#pragma unroll
    for (int ks = 0; ks < 2; ++ks) {
      const int kk = ks * 32 + (lane >> 4) * 8;
      short8 af[4], bfv[4];
#pragma unroll
      for (int i = 0; i < 4; ++i)
        af[i] = *reinterpret_cast<const short8*>(
            &As[(waveM * 64 + i * 16 + (lane & 15)) * 64 + kk]);
#pragma unroll
      for (int j = 0; j < 4; ++j)
        bfv[j] = *reinterpret_cast<const short8*>(
            &Bs[(waveN * 64 + j * 16 + (lane & 15)) * 64 + kk]);
#pragma unroll
      for (int i = 0; i < 4; ++i)
#pragma unroll
        for (int j = 0; j < 4; ++j)
          acc[i][j] = __builtin_amdgcn_mfma_f32_16x16x32_bf16(af[i], bfv[j], acc[i][j], 0, 0, 0);
    }
    __syncthreads();
  }

  // ---- epilogue: bias+act, stage bf16 tile in LDS, vectorized store ----
  // C/D layout: row=(lane>>4)*4+reg, col=lane&15  [m89-verified]
#pragma unroll
  for (int j = 0; j < 4; ++j) {
    const int colL = waveN * 64 + j * 16 + (lane & 15);   // 0..127
    const int colG = tileN + colL;
    float bv;
    if (BIASMODE == BIAS_QKV) {
      if (colG < 1024) bv = bias0[colG];
      else if (colG < 2048) bv = 0.f;
      else bv = bias1[colG - 2048];
    } else {
      bv = bias0[colG];
    }
#pragma unroll
    for (int i = 0; i < 4; ++i) {
      const int rL = waveM * 64 + i * 16 + ((lane >> 4) * 4);
#pragma unroll
      for (int r = 0; r < 4; ++r) {
        float v = acc[i][j][r] + bv;
        if (ACT == ACT_GELU) v = gelu_fast(v);
        sh[(rL + r) * 136 + colL] = f2bf_bits(v);
      }
    }
  }
  __syncthreads();
  {
    const int rowR = tid >> 4;          // 0..15
    const int colR = (tid & 15) * 8;    // 0..120, 16B-aligned
#pragma unroll
    for (int s = 0; s < 8; ++s) {
      const int row = s * 16 + rowR;
      uint4 val = *reinterpret_cast<const uint4*>(&sh[row * 136 + colR]);
      *reinterpret_cast<uint4*>(
          (unsigned short*)C + (size_t)(tileM + row) * (size_t)N + tileN + colR) = val;
    }
  }
}

// CPB MLP: regenerate the static log-spaced coord table and run 2->512->16 MLP.
__global__ __launch_bounds__(512) void cpb_kernel(
    const float* __restrict__ w1, const float* __restrict__ b1,
    const float* __restrict__ w2, float* __restrict__ TBL)
{
  __shared__ float hid[512];
  const int i = blockIdx.x;   // 0..224
  const int j = threadIdx.x;  // 0..511
  const float d0 = ((float)(i / 15) - 7.f) / 7.f;
  const float d1 = ((float)(i % 15) - 7.f) / 7.f;
  const float t0 = copysignf(log2f(1.f + fabsf(d0)), d0);
  const float t1 = copysignf(log2f(1.f + fabsf(d1)), d1);
  float hv = t0 * w1[j * 2] + t1 * w1[j * 2 + 1] + b1[j];
  hid[j] = fmaxf(hv, 0.f);
  __syncthreads();
  if (j < 16) {
    float s = 0.f;
    for (int jj = 0; jj < 512; ++jj) s += w2[j * 512 + jj] * hid[jj];
    TBL[i * 16 + j] = 16.f / (1.f + expf(-s));
  }
}

// attention: one wave per (window, head). cosine attn + cpb bias + shift mask + softmax + PV.
__global__ __launch_bounds__(64) void attn_kernel(
    const bf16* __restrict__ QKV, const float* __restrict__ TBL,
    const float* __restrict__ ls, bf16* __restrict__ ATT)
{
  __shared__ __align__(16) float kn[64][68];
  __shared__ __align__(16) float vvs[64][68];
  __shared__ float tb[225];
  __shared__ int ids[64];

  const int bw = blockIdx.x >> 4, h = blockIdx.x & 15;
  const int t = threadIdx.x;
  const unsigned short* qkvu = (const unsigned short*)QKV;
  const size_t rb = (size_t)(bw * 64 + t) * 3072;

  float q[64];
  float s2 = 0.f;
#pragma unroll
  for (int d0 = 0; d0 < 64; d0 += 8) {
    short8 v = *reinterpret_cast<const short8*>(&qkvu[rb + h * 64 + d0]);
#pragma unroll
    for (int j = 0; j < 8; ++j) { float f = bf2f((unsigned short)v[j]); q[d0 + j] = f; s2 += f * f; }
  }
  float inv = 1.f / fmaxf(sqrtf(s2), 1e-12f);
#pragma unroll
  for (int d = 0; d < 64; ++d) q[d] *= inv;

  s2 = 0.f;
#pragma unroll
  for (int d0 = 0; d0 < 64; d0 += 8) {
    short8 v = *reinterpret_cast<const short8*>(&qkvu[rb + 1024 + h * 64 + d0]);
#pragma unroll
    for (int j = 0; j < 8; ++j) { float f = bf2f((unsigned short)v[j]); kn[t][d0 + j] = f; s2 += f * f; }
  }
  inv = 1.f / fmaxf(sqrtf(s2), 1e-12f);
#pragma unroll
  for (int d = 0; d < 64; ++d) kn[t][d] *= inv;

#pragma unroll
  for (int d0 = 0; d0 < 64; d0 += 8) {
    short8 v = *reinterpret_cast<const short8*>(&qkvu[rb + 2048 + h * 64 + d0]);
#pragma unroll
    for (int j = 0; j < 8; ++j) vvs[t][d0 + j] = bf2f((unsigned short)v[j]);
  }

  for (int i = t; i < 225; i += 64) tb[i] = TBL[i * 16 + h];

  {
    const int w2 = bw & 3, wi = w2 >> 1, wj = w2 & 1;
    const int r = t >> 3, c = t & 7;
    const int gr = wi * 8 + r, gc = wj * 8 + c;
    const int rr = (gr < 8) ? 0 : ((gr < 12) ? 1 : 2);
    const int rc = (gc < 8) ? 0 : ((gc < 12) ? 1 : 2);
    ids[t] = rr * 3 + rc;
  }
  __syncthreads();

  const float scale = expf(fminf(ls[h], 4.60517019f));
  const int rt = t >> 3, ct = t & 7;
  const int myid = ids[t];

  float sc[64];
#pragma unroll
  for (int m = 0; m < 64; ++m) {
    const floatx4* kr = reinterpret_cast<const floatx4*>(&kn[m][0]);
    float dot = 0.f;
#pragma unroll
    for (int dq = 0; dq < 16; ++dq) {
      floatx4 kv = kr[dq];
      dot += q[4 * dq + 0] * kv[0] + q[4 * dq + 1] * kv[1] +
             q[4 * dq + 2] * kv[2] + q[4 * dq + 3] * kv[3];
    }
    const int rm = m >> 3, cm = m & 7;
    const int idx = (rt - rm + 7) * 15 + (ct - cm + 7);
    float val = dot * scale + tb[idx];
    if (ids[m] != myid) val -= 100.f;
    sc[m] = val;
  }

  float mx = -1e30f;
#pragma unroll
  for (int m = 0; m < 64; ++m) mx = fmaxf(mx, sc[m]);
  float ssum = 0.f;
#pragma unroll
  for (int m = 0; m < 64; ++m) { float e = expf(sc[m] - mx); sc[m] = e; ssum += e; }
  const float rs = 1.f / ssum;

  float out[64];
#pragma unroll
  for (int d = 0; d < 64; ++d) out[d] = 0.f;
#pragma unroll
  for (int m = 0; m < 64; ++m) {
    const float p = sc[m];
    const floatx4* vr = reinterpret_cast<const floatx4*>(&vvs[m][0]);
#pragma unroll
    for (int dq = 0; dq < 16; ++dq) {
      floatx4 vv = vr[dq];
      out[4 * dq + 0] += p * vv[0];
      out[4 * dq + 1] += p * vv[1];
      out[4 * dq + 2] += p * vv[2];
      out[4 * dq + 3] += p * vv[3];
    }
  }

  unsigned short* op = (unsigned short*)ATT + (size_t)(bw * 64 + t) * 1024 + h * 64;
#pragma unroll
  for (int d0 = 0; d0 < 64; d0 += 8) {
    union { short8 v; unsigned short u[8]; } o;
#pragma unroll
    for (int j = 0; j < 8; ++j) o.u[j] = f2bf_bits(out[d0 + j] * rs);
    *reinterpret_cast<short8*>(&op[d0]) = o.v;
  }
}

// out[tok] = base[tok] + LN(src[maprow(tok)]). One WAVE per token, 4 tokens/block.
// src bf16; base/out f32. WB additionally emits a bf16 copy of out.
template <bool GATHER, bool WB>
__global__ __launch_bounds__(256) void ln_residual(
    const bf16* __restrict__ src, const float* base,
    const float* __restrict__ gw, const float* __restrict__ gb,
    float* out, bf16* __restrict__ out_bf)
{
  const int tok = blockIdx.x * 4 + (threadIdx.x >> 6);
  const int lane = threadIdx.x & 63;
  int srow;
  if (GATHER) {
    const int bt = tok >> 8, rem = tok & 255, i = rem >> 4, j = rem & 15;
    const int p = (i + 12) & 15, qq = (j + 12) & 15;
    srow = (bt * 4 + (p >> 3) * 2 + (qq >> 3)) * 64 + (p & 7) * 8 + (qq & 7);
  } else {
    srow = tok;
  }
  const unsigned short* sp = (const unsigned short*)src + (size_t)srow * 1024 + lane * 16;
  short8 lv0 = *reinterpret_cast<const short8*>(sp);
  short8 lv1 = *reinterpret_cast<const short8*>(sp + 8);
  float v[16];
  float s = 0.f, sq = 0.f;
#pragma unroll
  for (int u = 0; u < 8; ++u) {
    float f = bf2f((unsigned short)lv0[u]); v[u] = f; s += f; sq += f * f;
    float g = bf2f((unsigned short)lv1[u]); v[u + 8] = g; s += g; sq += g * g;
  }
#pragma unroll
  for (int off = 32; off > 0; off >>= 1) { s += __shfl_xor(s, off); sq += __shfl_xor(sq, off); }
  const float mean = s * (1.f / 1024.f);
  const float var = sq * (1.f / 1024.f) - mean * mean;
  const float rstd = rsqrtf(var + 1e-5f);

  const float* bp = base + (size_t)tok * 1024 + lane * 16;
  float* op = out + (size_t)tok * 1024 + lane * 16;
  unsigned short* obp = WB ? ((unsigned short*)out_bf + (size_t)tok * 1024 + lane * 16) : nullptr;
  union { short8 v; unsigned short u[8]; } ob0, ob1;
#pragma unroll
  for (int q4 = 0; q4 < 4; ++q4) {
    float4 b4 = *reinterpret_cast<const float4*>(bp + q4 * 4);
    float bl[4] = {b4.x, b4.y, b4.z, b4.w};
    float4 o4;
    float* ol = (float*)&o4;
#pragma unroll
    for (int u = 0; u < 4; ++u) {
      const int c = lane * 16 + q4 * 4 + u;
      ol[u] = bl[u] + (v[q4 * 4 + u] - mean) * rstd * gw[c] + gb[c];
      if (WB) {
        if (q4 < 2) ob0.u[q4 * 4 + u] = f2bf_bits(ol[u]);
        else ob1.u[(q4 - 2) * 4 + u] = f2bf_bits(ol[u]);
      }
    }
    *reinterpret_cast<float4*>(op + q4 * 4) = o4;
  }
  if (WB) {
    *reinterpret_cast<short8*>(obp) = ob0.v;
    *reinterpret_cast<short8*>(obp + 8) = ob1.v;
  }
}

extern "C" void kernel_launch(void* const* d_in, const int* in_sizes, int n_in,
                              void* d_out, int out_size, void* d_ws, size_t ws_size,
                              hipStream_t stream) {
  (void)in_sizes; (void)n_in; (void)out_size; (void)ws_size;
  const float* x      = (const float*)d_in[0];
  const float* qkv_w  = (const float*)d_in[1];
  const float* q_bias = (const float*)d_in[2];
  const float* v_bias = (const float*)d_in[3];
  const float* lscale = (const float*)d_in[4];
  const float* cpb_w1 = (const float*)d_in[5];
  const float* cpb_b1 = (const float*)d_in[6];
  const float* cpb_w2 = (const float*)d_in[7];
  const float* proj_w = (const float*)d_in[8];
  const float* proj_b = (const float*)d_in[9];
  const float* n1w    = (const float*)d_in[10];
  const float* n1b    = (const float*)d_in[11];
  const float* fc1_w  = (const float*)d_in[12];
  const float* fc1_b  = (const float*)d_in[13];
  const float* fc2_w  = (const float*)d_in[14];
  const float* fc2_b  = (const float*)d_in[15];
  const float* n2w    = (const float*)d_in[16];
  const float* n2b    = (const float*)d_in[17];
  float* out = (float*)d_out;   // reference output dtype is float32

  // Chunked over 4 groups of 8192 tokens (32 images, window-aligned).
  // Region time-sharing (peak 100.7 MB):
  //  A [0, 67.1MB): QKV (50.3MB) -> H (67.1MB); tail [50.3,52.4MB) = proj_w bf16
  //  B [67.1, 83.9MB): qkv_w bf16 -> ATT -> XS_bf -> F2
  //  C [83.9, 100.7MB): x bf16 -> PROJ -> {fc1_w bf16, fc2_w bf16}
  //  TBL at 100.66MB
  char* ws = (char*)d_ws;
  bf16*  QKV  = (bf16*)(ws);                          // [8192,3072]
  bf16*  H    = (bf16*)(ws);                          // [8192,4096]
  bf16*  WPROJ= (bf16*)(ws + 50331648);               // [1024,1024]
  bf16*  WQKV = (bf16*)(ws + 67108864);               // [3072,1024]
  bf16*  ATT  = (bf16*)(ws + 67108864);               // [8192,1024]
  bf16*  XSB  = (bf16*)(ws + 67108864);               // [8192,1024]
  bf16*  F2   = (bf16*)(ws + 67108864);               // [8192,1024]
  bf16*  XBF  = (bf16*)(ws + 83886080);               // [8192,1024]
  bf16*  PROJ = (bf16*)(ws + 83886080);               // [8192,1024]
  bf16*  WF1  = (bf16*)(ws + 83886080);               // [4096,1024]
  bf16*  WF2  = (bf16*)(ws + 83886080 + 8388608);     // [1024,4096]
  float* TBL  = (float*)(ws + 100663296);             // [225,16] f32

  cpb_kernel<<<225, 512, 0, stream>>>(cpb_w1, cpb_b1, cpb_w2, TBL);

  for (int ch = 0; ch < 4; ++ch) {
    const size_t tokBase = (size_t)ch * 8192;
    const float* x_c = x + tokBase * 1024;
    float* out_c = out + tokBase * 1024;

    // pre-convert inputs/weights to bf16 (off the GEMM critical path)
    cvt_bf16<<<4096, 256, 0, stream>>>(x_c, XBF, 8388608);
    cvt_bf16<<<1536, 256, 0, stream>>>(qkv_w, WQKV, 3145728);
    cvt_bf16<<<512, 256, 0, stream>>>(proj_w, WPROJ, 1048576);

    // QKV with fused shift+window gather (chunk-local rows; images self-contained)
    gemm_bt<1, BIAS_QKV, ACT_NONE><<<dim3(64, 24), 256, 0, stream>>>(
        (const unsigned short*)XBF, (const unsigned short*)WQKV,
        q_bias, v_bias, QKV, 8192, 3072, 1024);
    // 128 windows x 16 heads (overwrites WQKV region with ATT - WQKV dead)
    attn_kernel<<<2048, 64, 0, stream>>>(QKV, TBL, lscale, ATT);
    gemm_bt<0, BIAS_SIMPLE, ACT_NONE><<<dim3(64, 8), 256, 0, stream>>>(
        (const unsigned short*)ATT, (const unsigned short*)WPROJ,
        proj_b, nullptr, PROJ, 8192, 1024, 1024);
    // window-reverse + roll + LN + residual; xs chunk lives in d_out (f32),
    // plus bf16 copy (XSB) for fc1's A operand
    ln_residual<true, true><<<2048, 256, 0, stream>>>(PROJ, x_c, n1w, n1b, out_c, XSB);
    // MLP weights -> bf16 (PROJ dead after ln1; reuse region C)
    cvt_bf16<<<2048, 256, 0, stream>>>(fc1_w, WF1, 4194304);
    cvt_bf16<<<2048, 256, 0, stream>>>(fc2_w, WF2, 4194304);
    gemm_bt<0, BIAS_SIMPLE, ACT_GELU><<<dim3(64, 32), 256, 0, stream>>>(
        (const unsigned short*)XSB, (const unsigned short*)WF1,
        fc1_b, nullptr, H, 8192, 4096, 1024);
    gemm_bt<0, BIAS_SIMPLE, ACT_NONE><<<dim3(64, 8), 256, 0, stream>>>(
        (const unsigned short*)H, (const unsigned short*)WF2,
        fc2_b, nullptr, F2, 8192, 1024, 4096);
    ln_residual<false, false><<<2048, 256, 0, stream>>>(F2, out_c, n2w, n2b, out_c, nullptr);
  }
}

// Round 3
// 1659.621 us; speedup vs baseline: 1.8900x; 1.2255x over previous
//
#include <hip/hip_runtime.h>
#include <hip/hip_bf16.h>
#include <math.h>

typedef __hip_bfloat16 bf16;
typedef __attribute__((ext_vector_type(8))) short short8;
typedef __attribute__((ext_vector_type(4))) short short4v;
typedef __attribute__((ext_vector_type(4))) float floatx4;
typedef __attribute__((ext_vector_type(2))) unsigned int uint2v;

#define DEV static __device__ __forceinline__

DEV float bf2f(unsigned short u) {
  union { unsigned int i; float f; } x;
  x.i = ((unsigned int)u) << 16;
  return x.f;
}
DEV unsigned short f2bf_bits(float f) {
  union { bf16 h; unsigned short u; } x;
  x.h = __float2bfloat16(f);
  return x.u;
}
DEV short8 cvt8(float4 a, float4 b) {
  short8 r;
  r[0] = (short)f2bf_bits(a.x); r[1] = (short)f2bf_bits(a.y);
  r[2] = (short)f2bf_bits(a.z); r[3] = (short)f2bf_bits(a.w);
  r[4] = (short)f2bf_bits(b.x); r[5] = (short)f2bf_bits(b.y);
  r[6] = (short)f2bf_bits(b.z); r[7] = (short)f2bf_bits(b.w);
  return r;
}

// tanh-form GELU: v * sigmoid(1.5957691*v + 0.0713548*v^3). |err| vs exact ~1e-3.
DEV float gelu_fast(float v) {
  float y = v * (1.5957691216f + 0.0713548163f * v * v);
  return __fdividef(v, 1.f + __expf(-y));
}

// async global->LDS, 16B per lane. LDS dest must be wave-uniform base + lane*16.
DEV void gload_lds16(const unsigned short* g, unsigned short* l) {
  __builtin_amdgcn_global_load_lds((const __attribute__((address_space(1))) void*)g,
                                   (__attribute__((address_space(3))) void*)l,
                                   16, 0, 0);
}

// window-gather (chunk-local): window-row -> source row (fuses roll(-4,-4)+partition)
DEV int gather_win_row(int wr) {
  int bw = wr >> 6, n = wr & 63;
  int bt = bw >> 2, w2 = bw & 3;
  int wi = w2 >> 1, wj = w2 & 1;
  int r = n >> 3, c = n & 7;
  int sr = (wi * 8 + r + 4) & 15;
  int sc = (wj * 8 + c + 4) & 15;
  return bt * 256 + sr * 16 + sc;
}

enum { BIAS_SIMPLE = 0, BIAS_QKV = 1 };
enum { ACT_NONE = 0, ACT_GELU = 1 };

// f32 -> bf16 bulk convert, 8 elems/thread.
__global__ __launch_bounds__(256) void cvt_bf16(const float* __restrict__ in,
                                                bf16* __restrict__ out, int n) {
  int i = (blockIdx.x * 256 + threadIdx.x) * 8;
  if (i >= n) return;
  float4 a = *reinterpret_cast<const float4*>(in + i);
  float4 b = *reinterpret_cast<const float4*>(in + i + 4);
  *reinterpret_cast<short8*>((unsigned short*)out + i) = cvt8(a, b);
}

// C[M,N] = act(A[M,K] @ B[N,K]^T + bias). A,B bf16 (pre-converted), bias f32,
// C bf16, fp32 accum via MFMA. BM=BN=128, BK=64, 256 threads = 4 waves (2x2).
// m97 structure: global_load_lds dwordx4 staging, 2-barrier K-loop.
// Epilogue: LDS transpose ([128][136] bf16, 16B-aligned rows) -> dwordx4 stores.
template <int GATHER, int BIASMODE, int ACT>
__global__ __launch_bounds__(256, 2) void gemm_bt(
    const unsigned short* __restrict__ A, const unsigned short* __restrict__ B,
    const float* __restrict__ bias0, const float* __restrict__ bias1,
    bf16* __restrict__ C, int M, int N, int K)
{
  // staging (2x 8192 shorts = 32KB) and epilogue tile (128*136 shorts = 34KB) share
  __shared__ __align__(16) unsigned short sh[128 * 136];
  unsigned short* As = sh;
  unsigned short* Bs = sh + 8192;

  const int tid = threadIdx.x;
  const int lane = tid & 63;
  const int wave = tid >> 6;
  const int waveM = wave >> 1, waveN = wave & 1;
  const int tileM = blockIdx.x * 128, tileN = blockIdx.y * 128;

  const int row0 = tid >> 3;          // 0..31
  const int kOff = (tid & 7) * 8;     // bf16 elem offset within row (16B steps)

  const unsigned short* ag[4];
  const unsigned short* bg[4];
  unsigned short* al[4];
  unsigned short* bl[4];
#pragma unroll
  for (int t = 0; t < 4; ++t) {
    int gr = tileM + row0 + 32 * t;
    int sr = GATHER ? gather_win_row(gr) : gr;
    ag[t] = A + (size_t)sr * (size_t)K + (size_t)kOff;
    bg[t] = B + (size_t)(tileN + row0 + 32 * t) * (size_t)K + (size_t)kOff;
    al[t] = &As[(row0 + 32 * t) * 64 + kOff];
    bl[t] = &Bs[(row0 + 32 * t) * 64 + kOff];
  }

  floatx4 acc[4][4];
#pragma unroll
  for (int i = 0; i < 4; ++i)
#pragma unroll
    for (int j = 0; j < 4; ++j) acc[i][j] = (floatx4){0.f, 0.f, 0.f, 0.f};

  for (int k0 = 0; k0 < K; k0 += 64) {
#pragma unroll
    for (int t = 0; t < 4; ++t) {
      gload_lds16(ag[t] + k0, al[t]);
      gload_lds16(bg[t] + k0, bl[t]);
    }
    __syncthreads();   // drains vmcnt -> LDS tile ready
#pragma unroll
    for (int ks = 0; ks < 2; ++ks) {
      const int kk = ks * 32 + (lane >> 4) * 8;
      short8 af[4], bfv[4];
#pragma unroll
      for (int i = 0; i < 4; ++i)
        af[i] = *reinterpret_cast<const short8*>(
            &As[(waveM * 64 + i * 16 + (lane & 15)) * 64 + kk]);
#pragma unroll
      for (int j = 0; j < 4; ++j)
        bfv[j] = *reinterpret_cast<const short8*>(
            &Bs[(waveN * 64 + j * 16 + (lane & 15)) * 64 + kk]);
#pragma unroll
      for (int i = 0; i < 4; ++i)
#pragma unroll
        for (int j = 0; j < 4; ++j)
          acc[i][j] = __builtin_amdgcn_mfma_f32_16x16x32_bf16(af[i], bfv[j], acc[i][j], 0, 0, 0);
    }
    __syncthreads();
  }

  // ---- epilogue: bias+act, stage bf16 tile in LDS, vectorized store ----
  // C/D layout: row=(lane>>4)*4+reg, col=lane&15  [m89-verified]
#pragma unroll
  for (int j = 0; j < 4; ++j) {
    const int colL = waveN * 64 + j * 16 + (lane & 15);   // 0..127
    const int colG = tileN + colL;
    float bv;
    if (BIASMODE == BIAS_QKV) {
      if (colG < 1024) bv = bias0[colG];
      else if (colG < 2048) bv = 0.f;
      else bv = bias1[colG - 2048];
    } else {
      bv = bias0[colG];
    }
#pragma unroll
    for (int i = 0; i < 4; ++i) {
      const int rL = waveM * 64 + i * 16 + ((lane >> 4) * 4);
#pragma unroll
      for (int r = 0; r < 4; ++r) {
        float v = acc[i][j][r] + bv;
        if (ACT == ACT_GELU) v = gelu_fast(v);
        sh[(rL + r) * 136 + colL] = f2bf_bits(v);
      }
    }
  }
  __syncthreads();
  {
    const int rowR = tid >> 4;          // 0..15
    const int colR = (tid & 15) * 8;    // 0..120, 16B-aligned
#pragma unroll
    for (int s = 0; s < 8; ++s) {
      const int row = s * 16 + rowR;
      uint4 val = *reinterpret_cast<const uint4*>(&sh[row * 136 + colR]);
      *reinterpret_cast<uint4*>(
          (unsigned short*)C + (size_t)(tileM + row) * (size_t)N + tileN + colR) = val;
    }
  }
}

// CPB MLP: regenerate the static log-spaced coord table and run 2->512->16 MLP.
// TBL layout: [16 heads][225] f32 (head-major for wave-contiguous loads).
__global__ __launch_bounds__(512) void cpb_kernel(
    const float* __restrict__ w1, const float* __restrict__ b1,
    const float* __restrict__ w2, float* __restrict__ TBL)
{
  __shared__ float hid[512];
  const int i = blockIdx.x;   // 0..224
  const int j = threadIdx.x;  // 0..511
  const float d0 = ((float)(i / 15) - 7.f) / 7.f;
  const float d1 = ((float)(i % 15) - 7.f) / 7.f;
  const float t0 = copysignf(log2f(1.f + fabsf(d0)), d0);
  const float t1 = copysignf(log2f(1.f + fabsf(d1)), d1);
  float hv = t0 * w1[j * 2] + t1 * w1[j * 2 + 1] + b1[j];
  hid[j] = fmaxf(hv, 0.f);
  __syncthreads();
  if (j < 16) {
    float s = 0.f;
    for (int jj = 0; jj < 512; ++jj) s += w2[j * 512 + jj] * hid[jj];
    TBL[j * 225 + i] = 16.f / (1.f + expf(-s));
  }
}

// MFMA attention: one wave per (window, head); block = 1 window x 4 heads.
// S^T = mfma(K, Q) (raw dots); cosine scaling applied as dot*rk[m]*rq[n]*scale.
// Softmax over keys m = rows of S^T: 16 local values/lane + shfl_xor(16,32).
// P -> bf16 -> LDS [64][72] -> A-frags; V^T frags via scalar u16 global loads.
__global__ __launch_bounds__(256) void attn_mfma(
    const bf16* __restrict__ QKV, const float* __restrict__ TBL,
    const float* __restrict__ ls, bf16* __restrict__ ATT)
{
  __shared__ __align__(16) unsigned short Ps[4][64][72];
  __shared__ float tbs[4][226];
  __shared__ int ids[64];

  const int tid = threadIdx.x;
  const int w = tid >> 6;        // wave = head sub-index
  const int l = tid & 63;
  const int q = l & 15;
  const int g = l >> 4;
  const int bw = blockIdx.x >> 2;
  const int h = (blockIdx.x & 3) * 4 + w;

  const unsigned short* qkvu = (const unsigned short*)QKV;
  const size_t rbase = (size_t)(bw * 64) * 3072;

  if (tid < 64) {
    const int w2 = bw & 3, wi = w2 >> 1, wj = w2 & 1;
    const int r = tid >> 3, c = tid & 7;
    const int rr = (wi == 0) ? 0 : (r < 4 ? 1 : 2);
    const int rc = (wj == 0) ? 0 : (c < 4 ? 1 : 2);
    ids[tid] = rr * 3 + rc;
  }
#pragma unroll
  for (int i = 0; i < 4; ++i) {
    int idx = i * 64 + l;
    if (idx < 225) tbs[w][idx] = TBL[h * 225 + idx];
  }
  __syncthreads();

  // --- Q,K fragments direct from global (16B per lane per frag) ---
  short8 kf[4][2], qf[4][2];
#pragma unroll
  for (int i = 0; i < 4; ++i) {
    const unsigned short* rp = qkvu + rbase + (size_t)(16 * i + q) * 3072 + h * 64 + g * 8;
    qf[i][0] = *reinterpret_cast<const short8*>(rp);
    qf[i][1] = *reinterpret_cast<const short8*>(rp + 32);
    kf[i][0] = *reinterpret_cast<const short8*>(rp + 1024);
    kf[i][1] = *reinterpret_cast<const short8*>(rp + 1024 + 32);
  }

  // --- L2 norms of q,k rows (f32, from bf16 values — same as reference) ---
  float rk4[4], rq4[4];
#pragma unroll
  for (int i = 0; i < 4; ++i) {
    float sk = 0.f, sq = 0.f;
#pragma unroll
    for (int ks = 0; ks < 2; ++ks)
#pragma unroll
      for (int e = 0; e < 8; ++e) {
        float kv = bf2f((unsigned short)kf[i][ks][e]);
        float qv = bf2f((unsigned short)qf[i][ks][e]);
        sk += kv * kv; sq += qv * qv;
      }
    sk += __shfl_xor(sk, 16); sk += __shfl_xor(sk, 32);
    sq += __shfl_xor(sq, 16); sq += __shfl_xor(sq, 32);
    rk4[i] = 1.f / fmaxf(sqrtf(sk), 1e-12f);
    rq4[i] = 1.f / fmaxf(sqrtf(sq), 1e-12f);
  }
  const float scl = expf(fminf(ls[h], 4.60517019f));
  float rqs[4];
#pragma unroll
  for (int j = 0; j < 4; ++j) rqs[j] = rq4[j] * scl;

  // --- S^T = K·Q^T (raw dots, f32 accum) ---
  floatx4 acc[4][4];
#pragma unroll
  for (int i = 0; i < 4; ++i)
#pragma unroll
    for (int j = 0; j < 4; ++j) acc[i][j] = (floatx4){0.f, 0.f, 0.f, 0.f};
#pragma unroll
  for (int ks = 0; ks < 2; ++ks)
#pragma unroll
    for (int i = 0; i < 4; ++i)
#pragma unroll
      for (int j = 0; j < 4; ++j)
        acc[i][j] = __builtin_amdgcn_mfma_f32_16x16x32_bf16(kf[i][ks], qf[j][ks], acc[i][j], 0, 0, 0);

  // --- V^T fragments (issued early; latency hidden under softmax VALU) ---
  // lane needs V[m = ks*32+g*8+e][d = 16*jp+q]: 8 scalar u16, full 32B sectors.
  short8 vf[4][2];
  const unsigned short* vbase = qkvu + rbase + 2048 + h * 64;
#pragma unroll
  for (int jp = 0; jp < 4; ++jp)
#pragma unroll
    for (int ks = 0; ks < 2; ++ks) {
      const int m0 = ks * 32 + g * 8;
      const unsigned short* vp = vbase + 16 * jp + q;
      union { short8 v; unsigned short u[8]; } pk;
#pragma unroll
      for (int e = 0; e < 8; ++e)
        pk.u[e] = vp[(size_t)(m0 + e) * 3072];
      vf[jp][ks] = pk.v;
    }

  // --- logits: cosine scale + cpb bias + shift mask (in place) ---
  int idn[4], rtn[4], ctn[4];
#pragma unroll
  for (int j = 0; j < 4; ++j) {
    const int n = 16 * j + q;
    rtn[j] = n >> 3; ctn[j] = n & 7; idn[j] = ids[n];
  }
#pragma unroll
  for (int i = 0; i < 4; ++i) {
#pragma unroll
    for (int r = 0; r < 4; ++r) {
      const int m = 16 * i + 4 * g + r;
      const float rkm = __shfl(rk4[i], 4 * g + r);
      const int rm = m >> 3, cm = m & 7;
      const int idm = ids[m];
#pragma unroll
      for (int j = 0; j < 4; ++j) {
        float v = acc[i][j][r] * (rkm * rqs[j]) +
                  tbs[w][(rtn[j] - rm + 7) * 15 + (ctn[j] - cm + 7)];
        if (idm != idn[j]) v -= 100.f;
        acc[i][j][r] = v;
      }
    }
  }

  // --- softmax over m (rows of S^T), per column n ---
  float rs4[4];
#pragma unroll
  for (int j = 0; j < 4; ++j) {
    float mx = acc[0][j][0];
#pragma unroll
    for (int i = 0; i < 4; ++i)
#pragma unroll
      for (int r = 0; r < 4; ++r) mx = fmaxf(mx, acc[i][j][r]);
    mx = fmaxf(mx, __shfl_xor(mx, 16));
    mx = fmaxf(mx, __shfl_xor(mx, 32));
    float sm = 0.f;
#pragma unroll
    for (int i = 0; i < 4; ++i)
#pragma unroll
      for (int r = 0; r < 4; ++r) {
        float e = __expf(acc[i][j][r] - mx);
        acc[i][j][r] = e; sm += e;
      }
    sm += __shfl_xor(sm, 16);
    sm += __shfl_xor(sm, 32);
    rs4[j] = 1.f / sm;
  }

  // --- P (bf16) -> Ps[n][m]; r-adjacent m values pack into one 8B write ---
#pragma unroll
  for (int j = 0; j < 4; ++j)
#pragma unroll
    for (int i = 0; i < 4; ++i) {
      uint2v pw;
      pw[0] = (unsigned int)f2bf_bits(acc[i][j][0]) |
              ((unsigned int)f2bf_bits(acc[i][j][1]) << 16);
      pw[1] = (unsigned int)f2bf_bits(acc[i][j][2]) |
              ((unsigned int)f2bf_bits(acc[i][j][3]) << 16);
      *reinterpret_cast<uint2v*>(&Ps[w][16 * j + q][16 * i + 4 * g]) = pw;
    }

  // --- PV: C[n][d] = P·V ---
  floatx4 o[4][4];
#pragma unroll
  for (int i = 0; i < 4; ++i)
#pragma unroll
    for (int j = 0; j < 4; ++j) o[i][j] = (floatx4){0.f, 0.f, 0.f, 0.f};
#pragma unroll
  for (int ks = 0; ks < 2; ++ks) {
    short8 pa[4];
#pragma unroll
    for (int i2 = 0; i2 < 4; ++i2)
      pa[i2] = *reinterpret_cast<const short8*>(&Ps[w][16 * i2 + q][ks * 32 + g * 8]);
#pragma unroll
    for (int i2 = 0; i2 < 4; ++i2)
#pragma unroll
      for (int j2 = 0; j2 < 4; ++j2)
        o[i2][j2] = __builtin_amdgcn_mfma_f32_16x16x32_bf16(pa[i2], vf[j2][ks], o[i2][j2], 0, 0, 0);
  }

  // --- store (apply deferred softmax denominator); 4x32B sectors per instr ---
  unsigned short* op = (unsigned short*)ATT + (size_t)(bw * 64) * 1024 + h * 64;
#pragma unroll
  for (int i2 = 0; i2 < 4; ++i2)
#pragma unroll
    for (int r = 0; r < 4; ++r) {
      const float rsn = __shfl(rs4[i2], 4 * g + r);
      const int row = 16 * i2 + 4 * g + r;
#pragma unroll
      for (int j2 = 0; j2 < 4; ++j2)
        op[(size_t)row * 1024 + 16 * j2 + q] = f2bf_bits(o[i2][j2][r] * rsn);
    }
}

// out[tok] = base[tok] + LN(src[maprow(tok)]). One WAVE per token, 4 tokens/block.
// src bf16; base/out f32. WB additionally emits a bf16 copy of out.
template <bool GATHER, bool WB>
__global__ __launch_bounds__(256) void ln_residual(
    const bf16* __restrict__ src, const float* base,
    const float* __restrict__ gw, const float* __restrict__ gb,
    float* out, bf16* __restrict__ out_bf)
{
  const int tok = blockIdx.x * 4 + (threadIdx.x >> 6);
  const int lane = threadIdx.x & 63;
  int srow;
  if (GATHER) {
    const int bt = tok >> 8, rem = tok & 255, i = rem >> 4, j = rem & 15;
    const int p = (i + 12) & 15, qq = (j + 12) & 15;
    srow = (bt * 4 + (p >> 3) * 2 + (qq >> 3)) * 64 + (p & 7) * 8 + (qq & 7);
  } else {
    srow = tok;
  }
  const unsigned short* sp = (const unsigned short*)src + (size_t)srow * 1024 + lane * 16;
  short8 lv0 = *reinterpret_cast<const short8*>(sp);
  short8 lv1 = *reinterpret_cast<const short8*>(sp + 8);
  float v[16];
  float s = 0.f, sq = 0.f;
#pragma unroll
  for (int u = 0; u < 8; ++u) {
    float f = bf2f((unsigned short)lv0[u]); v[u] = f; s += f; sq += f * f;
    float g = bf2f((unsigned short)lv1[u]); v[u + 8] = g; s += g; sq += g * g;
  }
#pragma unroll
  for (int off = 32; off > 0; off >>= 1) { s += __shfl_xor(s, off); sq += __shfl_xor(sq, off); }
  const float mean = s * (1.f / 1024.f);
  const float var = sq * (1.f / 1024.f) - mean * mean;
  const float rstd = rsqrtf(var + 1e-5f);

  const float* bp = base + (size_t)tok * 1024 + lane * 16;
  float* op = out + (size_t)tok * 1024 + lane * 16;
  unsigned short* obp = WB ? ((unsigned short*)out_bf + (size_t)tok * 1024 + lane * 16) : nullptr;
  union { short8 v; unsigned short u[8]; } ob0, ob1;
#pragma unroll
  for (int q4 = 0; q4 < 4; ++q4) {
    float4 b4 = *reinterpret_cast<const float4*>(bp + q4 * 4);
    float bl[4] = {b4.x, b4.y, b4.z, b4.w};
    float4 o4;
    float* ol = (float*)&o4;
#pragma unroll
    for (int u = 0; u < 4; ++u) {
      const int c = lane * 16 + q4 * 4 + u;
      ol[u] = bl[u] + (v[q4 * 4 + u] - mean) * rstd * gw[c] + gb[c];
      if (WB) {
        if (q4 < 2) ob0.u[q4 * 4 + u] = f2bf_bits(ol[u]);
        else ob1.u[(q4 - 2) * 4 + u] = f2bf_bits(ol[u]);
      }
    }
    *reinterpret_cast<float4*>(op + q4 * 4) = o4;
  }
  if (WB) {
    *reinterpret_cast<short8*>(obp) = ob0.v;
    *reinterpret_cast<short8*>(obp + 8) = ob1.v;
  }
}

extern "C" void kernel_launch(void* const* d_in, const int* in_sizes, int n_in,
                              void* d_out, int out_size, void* d_ws, size_t ws_size,
                              hipStream_t stream) {
  (void)in_sizes; (void)n_in; (void)out_size;
  const float* x      = (const float*)d_in[0];
  const float* qkv_w  = (const float*)d_in[1];
  const float* q_bias = (const float*)d_in[2];
  const float* v_bias = (const float*)d_in[3];
  const float* lscale = (const float*)d_in[4];
  const float* cpb_w1 = (const float*)d_in[5];
  const float* cpb_b1 = (const float*)d_in[6];
  const float* cpb_w2 = (const float*)d_in[7];
  const float* proj_w = (const float*)d_in[8];
  const float* proj_b = (const float*)d_in[9];
  const float* n1w    = (const float*)d_in[10];
  const float* n1b    = (const float*)d_in[11];
  const float* fc1_w  = (const float*)d_in[12];
  const float* fc1_b  = (const float*)d_in[13];
  const float* fc2_w  = (const float*)d_in[14];
  const float* fc2_b  = (const float*)d_in[15];
  const float* n2w    = (const float*)d_in[16];
  const float* n2b    = (const float*)d_in[17];
  float* out = (float*)d_out;   // reference output dtype is float32

  // Chunked over 4 groups of 8192 tokens (32 images, window-aligned).
  // Region time-sharing (peak 100.7 MB base; +25.2 MB persistent weights if ws allows):
  //  A [0, 67.1MB): QKV (50.3MB) -> H (67.1MB); tail [50.3,52.4MB) = proj_w bf16 (fallback)
  //  B [67.1, 83.9MB): qkv_w bf16 (fallback) -> ATT -> XSB -> F2
  //  C [83.9, 100.7MB): x bf16 -> PROJ -> {fc1_w, fc2_w bf16 (fallback)}
  //  TBL at 100.66MB; persistent weights (if ws_size >= 120MB) above TBL.
  char* ws = (char*)d_ws;
  bf16*  QKV  = (bf16*)(ws);                          // [8192,3072]
  bf16*  H    = (bf16*)(ws);                          // [8192,4096]
  bf16*  ATT  = (bf16*)(ws + 67108864);               // [8192,1024]
  bf16*  XSB  = (bf16*)(ws + 67108864);               // [8192,1024]
  bf16*  F2   = (bf16*)(ws + 67108864);               // [8192,1024]
  bf16*  XBF  = (bf16*)(ws + 83886080);               // [8192,1024]
  bf16*  PROJ = (bf16*)(ws + 83886080);               // [8192,1024]
  float* TBL  = (float*)(ws + 100663296);             // [16,225] f32

  const bool persist = ws_size >= (size_t)125845504;  // 120 MB
  bf16* WQKV, *WPROJ, *WF1, *WF2;
  if (persist) {
    WQKV  = (bf16*)(ws + 100679680);                  // 6.3 MB
    WPROJ = (bf16*)(ws + 106971136);                  // 2.1 MB
    WF1   = (bf16*)(ws + 109068288);                  // 8.4 MB
    WF2   = (bf16*)(ws + 117456896);                  // 8.4 MB
  } else {
    WQKV  = (bf16*)(ws + 67108864);                   // region B (pre-ATT)
    WPROJ = (bf16*)(ws + 50331648);                   // region A tail
    WF1   = (bf16*)(ws + 83886080);                   // region C (post-ln1)
    WF2   = (bf16*)(ws + 83886080 + 8388608);
  }

  cpb_kernel<<<225, 512, 0, stream>>>(cpb_w1, cpb_b1, cpb_w2, TBL);
  if (persist) {
    cvt_bf16<<<1536, 256, 0, stream>>>(qkv_w, WQKV, 3145728);
    cvt_bf16<<<512, 256, 0, stream>>>(proj_w, WPROJ, 1048576);
    cvt_bf16<<<2048, 256, 0, stream>>>(fc1_w, WF1, 4194304);
    cvt_bf16<<<2048, 256, 0, stream>>>(fc2_w, WF2, 4194304);
  }

  for (int ch = 0; ch < 4; ++ch) {
    const size_t tokBase = (size_t)ch * 8192;
    const float* x_c = x + tokBase * 1024;
    float* out_c = out + tokBase * 1024;

    cvt_bf16<<<4096, 256, 0, stream>>>(x_c, XBF, 8388608);
    if (!persist) {
      cvt_bf16<<<1536, 256, 0, stream>>>(qkv_w, WQKV, 3145728);
      cvt_bf16<<<512, 256, 0, stream>>>(proj_w, WPROJ, 1048576);
    }

    // QKV with fused shift+window gather (chunk-local rows; images self-contained)
    gemm_bt<1, BIAS_QKV, ACT_NONE><<<dim3(64, 24), 256, 0, stream>>>(
        (const unsigned short*)XBF, (const unsigned short*)WQKV,
        q_bias, v_bias, QKV, 8192, 3072, 1024);
    // 128 windows x 4 head-groups, 4 waves each
    attn_mfma<<<512, 256, 0, stream>>>(QKV, TBL, lscale, ATT);
    gemm_bt<0, BIAS_SIMPLE, ACT_NONE><<<dim3(64, 8), 256, 0, stream>>>(
        (const unsigned short*)ATT, (const unsigned short*)WPROJ,
        proj_b, nullptr, PROJ, 8192, 1024, 1024);
    // window-reverse + roll + LN + residual; xs chunk lives in d_out (f32),
    // plus bf16 copy (XSB) for fc1's A operand
    ln_residual<true, true><<<2048, 256, 0, stream>>>(PROJ, x_c, n1w, n1b, out_c, XSB);
    if (!persist) {
      cvt_bf16<<<2048, 256, 0, stream>>>(fc1_w, WF1, 4194304);
      cvt_bf16<<<2048, 256, 0, stream>>>(fc2_w, WF2, 4194304);
    }
    gemm_bt<0, BIAS_SIMPLE, ACT_GELU><<<dim3(64, 32), 256, 0, stream>>>(
        (const unsigned short*)XSB, (const unsigned short*)WF1,
        fc1_b, nullptr, H, 8192, 4096, 1024);
    gemm_bt<0, BIAS_SIMPLE, ACT_NONE><<<dim3(64, 8), 256, 0, stream>>>(
        (const unsigned short*)H, (const unsigned short*)WF2,
        fc2_b, nullptr, F2, 8192, 1024, 4096);
    ln_residual<false, false><<<2048, 256, 0, stream>>>(F2, out_c, n2w, n2b, out_c, nullptr);
  }
}